// Round 6
// baseline (677.925 us; speedup 1.0000x reference)
//
#include <hip/hip_runtime.h>
#include <math.h>

// Problem constants: S=512, B=256, V=100000, E=128, H=256
#define S_LEN 512
#define B_SZ  256
#define E_SZ  128
#define H_SZ  256
#define XSTP  65536  // floats per step in fragment-linear xproj layout (B*H)
                     // R5 BUG was 8192 (B*H/8): steps aliased -> absmax 1.84

typedef __attribute__((ext_vector_type(8))) short bf16x8;
typedef __attribute__((ext_vector_type(4))) float f32x4;

// W_ih pre-converted to bf16 hi/lo, stored in FRAGMENT-LINEAR order:
// idx = ((ht*4 + kk)*64 + lane)*8, element = W_ih[ht*16+(lane&15)][kk*32+(lane>>4)*8+j]
__device__ short g_wfh[H_SZ * E_SZ];   // 64 KB
__device__ short g_wfl[H_SZ * E_SZ];   // 64 KB

__device__ __forceinline__ unsigned pkbf(float a, float b) {
    unsigned r; asm("v_cvt_pk_bf16_f32 %0, %1, %2" : "=v"(r) : "v"(a), "v"(b));
    return r;   // lo16 = bf16(a), hi16 = bf16(b), RNE
}
__device__ __forceinline__ float fromlo(unsigned u) {
    union { unsigned u; float f; } c; c.u = u << 16; return c.f;
}
__device__ __forceinline__ float fromhi(unsigned u) {
    union { unsigned u; float f; } c; c.u = u & 0xffff0000u; return c.f;
}
__device__ __forceinline__ void cvt_hilo8(float4 a, float4 b, bf16x8& hi, bf16x8& lo) {
    unsigned h0 = pkbf(a.x, a.y), h1 = pkbf(a.z, a.w);
    unsigned h2 = pkbf(b.x, b.y), h3 = pkbf(b.z, b.w);
    unsigned l0 = pkbf(a.x - fromlo(h0), a.y - fromhi(h0));
    unsigned l1 = pkbf(a.z - fromlo(h1), a.w - fromhi(h1));
    unsigned l2 = pkbf(b.x - fromlo(h2), b.y - fromhi(h2));
    unsigned l3 = pkbf(b.z - fromlo(h3), b.w - fromhi(h3));
    union { bf16x8 v; unsigned u[4]; } H, L;
    H.u[0] = h0; H.u[1] = h1; H.u[2] = h2; H.u[3] = h3;
    L.u[0] = l0; L.u[1] = l1; L.u[2] = l2; L.u[3] = l3;
    hi = H.v; lo = L.v;
}

// tanh(v) = 1 - 2/(exp2(C*v)+1), C = 2*log2(e). Numerics validated in R4.
__device__ __forceinline__ float tanhC(float v) {
    float e = __builtin_amdgcn_exp2f(v * 2.8853900818f);
    return fmaf(-2.f, __builtin_amdgcn_rcpf(e + 1.f), 1.f);
}

// ---------------------------------------------------------------------------
// Kernel 0: one-time W_ih -> bf16 hi/lo in fragment-linear order.
// 16 blocks x 256 threads: t = ((ht*4+kk)*64 + lane)
// ---------------------------------------------------------------------------
__global__ void prep_w_kernel(const float* __restrict__ W_ih) {
    const int t  = blockIdx.x * 256 + threadIdx.x;   // 0..4095
    const int l  = t & 63;
    const int kk = (t >> 6) & 3;
    const int ht = t >> 8;                            // 0..15
    const int h  = ht * 16 + (l & 15);
    const int k0 = kk * 32 + (l >> 4) * 8;
    const float* wp = W_ih + h * E_SZ + k0;
    float4 a = *(const float4*)wp;
    float4 b = *(const float4*)(wp + 4);
    bf16x8 hi, lo;
    cvt_hilo8(a, b, hi, lo);
    *(bf16x8*)&g_wfh[t * 8] = hi;
    *(bf16x8*)&g_wfl[t * 8] = lo;
}

// ---------------------------------------------------------------------------
// Kernel 1 (v5): embed gather + projection, bf16 MFMA hi/lo split.
//  - W fragments from g_wfh/g_wfl: per wave-load 64 lanes x 16B CONTIGUOUS.
//  - xproj written in FRAGMENT-LINEAR layout: element (s, b, h) at
//    float idx s*XSTP + ((b>>4)*16 + ht)*256 + lane*4 + (h&3)
//    with ht = h>>4, lane = ((h>>2)&3)*16 + (b&15)
//    -> every wave-store is 1KB contiguous; scan's reads stream contiguously.
// ---------------------------------------------------------------------------
__global__ __launch_bounds__(256, 2) void embed_proj_mfma(
    const int*   __restrict__ X,
    const float* __restrict__ emb,
    const float* __restrict__ b_ih,
    const float* __restrict__ b_hh,
    float*       __restrict__ xproj)
{
    __shared__ int   toks[64];
    __shared__ short BtH[4][4][64][8];   // [ntile][kk][lane][j] hi, 16KB
    __shared__ short BtL[4][4][64][8];   // lo, 16KB

    const int tid  = threadIdx.x;
    const int wave = tid >> 6;           // 0..3
    const int lane = tid & 63;
    const int bl   = lane & 15;
    const int quad = lane >> 4;
    const size_t row0 = (size_t)blockIdx.x * 64;   // rows = s*256 + b
    const int s_idx = (int)(row0 >> 8);
    const int bbase = (int)(row0 & 255);

    if (tid < 64) toks[tid] = X[row0 + tid];
    __syncthreads();

    // ---- stage emb tile (hi/lo bf16) into B-frag-linear LDS (coalesced) ----
    {
        const int r  = tid >> 2;         // 0..63 row
        const int kk = tid & 3;          // k-chunk of 32
        const float* ep = emb + (size_t)toks[r] * E_SZ + kk * 32;
#pragma unroll
        for (int q = 0; q < 4; ++q) {
            float4 a = *(const float4*)(ep + q * 8);
            float4 b = *(const float4*)(ep + q * 8 + 4);
            bf16x8 fh, fl;
            cvt_hilo8(a, b, fh, fl);
            *(bf16x8*)&BtH[r >> 4][kk][q * 16 + (r & 15)][0] = fh;
            *(bf16x8*)&BtL[r >> 4][kk][q * 16 + (r & 15)][0] = fl;
        }
    }
    __syncthreads();

    // ---- compute: 2 passes x 2 m-tiles; D[m=h][n=row] = W_ih * Emb^T ----
#pragma unroll
    for (int mp = 0; mp < 2; ++mp) {
        bf16x8 wh[2][4], wl[2][4];
#pragma unroll
        for (int i = 0; i < 2; ++i) {
            const int ht = wave * 4 + mp * 2 + i;
#pragma unroll
            for (int kk = 0; kk < 4; ++kk) {
                wh[i][kk] = *(const bf16x8*)&g_wfh[((ht * 4 + kk) * 64 + lane) * 8];
                wl[i][kk] = *(const bf16x8*)&g_wfl[((ht * 4 + kk) * 64 + lane) * 8];
            }
        }

        f32x4 acc[2][4];
#pragma unroll
        for (int i = 0; i < 2; ++i)
#pragma unroll
            for (int nt = 0; nt < 4; ++nt) acc[i][nt] = (f32x4){0.f, 0.f, 0.f, 0.f};

#pragma unroll
        for (int kk = 0; kk < 4; ++kk) {
            bf16x8 bh[4], blo[4];
#pragma unroll
            for (int nt = 0; nt < 4; ++nt) {
                bh[nt]  = *(const bf16x8*)&BtH[nt][kk][lane][0];
                blo[nt] = *(const bf16x8*)&BtL[nt][kk][lane][0];
            }
#pragma unroll
            for (int i = 0; i < 2; ++i)
#pragma unroll
                for (int nt = 0; nt < 4; ++nt) {
                    f32x4 a = acc[i][nt];
                    a = __builtin_amdgcn_mfma_f32_16x16x32_bf16(wh[i][kk], bh[nt],  a, 0, 0, 0);
                    a = __builtin_amdgcn_mfma_f32_16x16x32_bf16(wh[i][kk], blo[nt], a, 0, 0, 0);
                    a = __builtin_amdgcn_mfma_f32_16x16x32_bf16(wl[i][kk], bh[nt],  a, 0, 0, 0);
                    acc[i][nt] = a;
                }
        }

        // epilogue: bias + fragment-linear store (1KB contiguous per wave-store)
#pragma unroll
        for (int i = 0; i < 2; ++i) {
            const int ht = wave * 4 + mp * 2 + i;
            const int hb = ht * 16 + quad * 4;
            float4 bi  = *(const float4*)&b_ih[hb];
            float4 bh4 = *(const float4*)&b_hh[hb];
#pragma unroll
            for (int nt = 0; nt < 4; ++nt) {
                const int b   = bbase + nt * 16;              // + bl via lane
                const int blk = b >> 5, str = (b >> 4) & 1;
                f32x4 o = acc[i][nt];
                o[0] += bi.x + bh4.x; o[1] += bi.y + bh4.y;
                o[2] += bi.z + bh4.z; o[3] += bi.w + bh4.w;
                float* dst = xproj + (size_t)s_idx * XSTP
                           + ((((blk * 2 + str) * 8 + (ht >> 1)) * 2 + (ht & 1)) * 64 + lane) * 4;
                *(f32x4*)dst = o;
            }
        }
    }
}

// ---------------------------------------------------------------------------
// Kernel 2 (v6): 8-wave MFMA scan, TWO independent batch streams per block.
// 8 blocks x 32 batch (streams A=b0..15, B=b16..31). Stream B's LDS reads
// overlap stream A's MFMA+tanh within each step; one barrier per step covers
// both. Keeps v3's proven prefetch (load directly into x-regs at step end,
// distance 2) + v5's validated C-init-with-xp and tanhC.
// ---------------------------------------------------------------------------
__global__ __launch_bounds__(512, 2) void rnn_scan_kernel(
    const float* __restrict__ xproj,
    const float* __restrict__ W_hh,
    float*       __restrict__ out)
{
    const int tid  = threadIdx.x;
    const int wave = tid >> 6;      // 0..7
    const int lane = tid & 63;
    const int bl   = lane & 15;
    const int quad = lane >> 4;
    const int B0   = blockIdx.x * 32;

    __shared__ short HB[2][2][4096];   // [buf][stream], 4 x 8KB
    __shared__ float sred[8][32];

    // ---- A-operand: W_hh fragments (shared by both streams) ----
    // lane holds A[m = wave*32 + mt*16 + bl][k = kk*32 + quad*8 + j]
    bf16x8 wfrag[2][8];
#pragma unroll
    for (int mt = 0; mt < 2; ++mt) {
        const int h = wave * 32 + mt * 16 + bl;
#pragma unroll
        for (int kk = 0; kk < 8; ++kk) {
            const float* wp = W_hh + (size_t)h * H_SZ + kk * 32 + quad * 8;
            float4 a = *(const float4*)wp;
            float4 b = *(const float4*)(wp + 4);
            union { bf16x8 v; unsigned u[4]; } F;
            F.u[0] = pkbf(a.x, a.y); F.u[1] = pkbf(a.z, a.w);
            F.u[2] = pkbf(b.x, b.y); F.u[3] = pkbf(b.z, b.w);
            wfrag[mt][kk] = F.v;
        }
    }

    // zero both streams' buf0 (16 KB)
    { int4* z = (int4*)&HB[0][0][0]; z[tid] = make_int4(0,0,0,0); z[tid+512] = make_int4(0,0,0,0); }

    const short* rdA0 = &HB[0][0][0] + lane * 8;
    const short* rdA1 = &HB[1][0][0] + lane * 8;
    const short* rdB0 = &HB[0][1][0] + lane * 8;
    const short* rdB1 = &HB[1][1][0] + lane * 8;

    // write slot for h = wave*32 + mt*16 + quad*4 + r:
    // shorts offset (h>>5)*512 + ((h>>3)&3)*128 + bl*8 + (h&7); mt -> +256
    const int wo = wave * 512 + (quad >> 1) * 128 + bl * 8 + (quad & 1) * 4;
    short* wA0 = &HB[0][0][0] + wo; short* wA1 = &HB[1][0][0] + wo;
    short* wB0 = &HB[0][1][0] + wo; short* wB1 = &HB[1][1][0] + wo;

    // xp bases, fragment-linear: within-step offset (blk2*16 + wave*2 + mt)*256 + lane*4
    const float* xpA = xproj + (size_t)((((blockIdx.x * 2 + 0) * 8 + wave) * 2) * 64 + lane) * 4;
    const float* xpB = xproj + (size_t)((((blockIdx.x * 2 + 1) * 8 + wave) * 2) * 64 + lane) * 4;

    // distance-2 prefetch register sets (per stream, even/odd parity); mt at +256 floats
    f32x4 xAe0 = *(const f32x4*)(xpA);          f32x4 xAe1 = *(const f32x4*)(xpA + 256);
    f32x4 xAo0 = *(const f32x4*)(xpA + XSTP);   f32x4 xAo1 = *(const f32x4*)(xpA + XSTP + 256);
    f32x4 xBe0 = *(const f32x4*)(xpB);          f32x4 xBe1 = *(const f32x4*)(xpB + 256);
    f32x4 xBo0 = *(const f32x4*)(xpB + XSTP);   f32x4 xBo1 = *(const f32x4*)(xpB + XSTP + 256);

    __syncthreads();

    auto do_step = [&](const short* rdA, short* wrA, f32x4& xa0, f32x4& xa1, const float* pfA,
                       const short* rdB, short* wrB, f32x4& xb0, f32x4& xb1, const float* pfB) {
        // issue ALL 16 ds_reads up front; B-stream reads complete under A's MFMAs
        bf16x8 fA[8], fB[8];
#pragma unroll
        for (int kk = 0; kk < 8; ++kk) fA[kk] = *(const bf16x8*)(rdA + kk * 512);
#pragma unroll
        for (int kk = 0; kk < 8; ++kk) fB[kk] = *(const bf16x8*)(rdB + kk * 512);

        // stream A: 4 chains of depth 4, xp as C-init of the first chain pair
        f32x4 Aa0 = xa0, Aa1 = xa1;
        f32x4 Ab0 = {0.f,0.f,0.f,0.f}, Ab1 = {0.f,0.f,0.f,0.f};
#pragma unroll
        for (int kk = 0; kk < 4; ++kk) {
            Aa0 = __builtin_amdgcn_mfma_f32_16x16x32_bf16(wfrag[0][kk],   fA[kk],   Aa0, 0, 0, 0);
            Aa1 = __builtin_amdgcn_mfma_f32_16x16x32_bf16(wfrag[1][kk],   fA[kk],   Aa1, 0, 0, 0);
            Ab0 = __builtin_amdgcn_mfma_f32_16x16x32_bf16(wfrag[0][kk+4], fA[kk+4], Ab0, 0, 0, 0);
            Ab1 = __builtin_amdgcn_mfma_f32_16x16x32_bf16(wfrag[1][kk+4], fA[kk+4], Ab1, 0, 0, 0);
        }
        // stream B
        f32x4 Ba0 = xb0, Ba1 = xb1;
        f32x4 Bb0 = {0.f,0.f,0.f,0.f}, Bb1 = {0.f,0.f,0.f,0.f};
#pragma unroll
        for (int kk = 0; kk < 4; ++kk) {
            Ba0 = __builtin_amdgcn_mfma_f32_16x16x32_bf16(wfrag[0][kk],   fB[kk],   Ba0, 0, 0, 0);
            Ba1 = __builtin_amdgcn_mfma_f32_16x16x32_bf16(wfrag[1][kk],   fB[kk],   Ba1, 0, 0, 0);
            Bb0 = __builtin_amdgcn_mfma_f32_16x16x32_bf16(wfrag[0][kk+4], fB[kk+4], Bb0, 0, 0, 0);
            Bb1 = __builtin_amdgcn_mfma_f32_16x16x32_bf16(wfrag[1][kk+4], fB[kk+4], Bb1, 0, 0, 0);
        }
        const f32x4 dA0 = Aa0 + Ab0, dA1 = Aa1 + Ab1;
        const f32x4 dB0 = Ba0 + Bb0, dB1 = Ba1 + Bb1;

        // epilogues: tanh, pack, store next state
        {
            float t0 = tanhC(dA0[0]), t1 = tanhC(dA0[1]), t2 = tanhC(dA0[2]), t3 = tanhC(dA0[3]);
            float u0 = tanhC(dA1[0]), u1 = tanhC(dA1[1]), u2 = tanhC(dA1[2]), u3 = tanhC(dA1[3]);
            *(uint2*)wrA         = make_uint2(pkbf(t0, t1), pkbf(t2, t3));
            *(uint2*)(wrA + 256) = make_uint2(pkbf(u0, u1), pkbf(u2, u3));
        }
        {
            float t0 = tanhC(dB0[0]), t1 = tanhC(dB0[1]), t2 = tanhC(dB0[2]), t3 = tanhC(dB0[3]);
            float u0 = tanhC(dB1[0]), u1 = tanhC(dB1[1]), u2 = tanhC(dB1[2]), u3 = tanhC(dB1[3]);
            *(uint2*)wrB         = make_uint2(pkbf(t0, t1), pkbf(t2, t3));
            *(uint2*)(wrB + 256) = make_uint2(pkbf(u0, u1), pkbf(u2, u3));
        }

        // prefetch for step s+2 directly into the just-consumed registers
        // (v3-proven: consumption is 2 full steps after issue; no early drain)
        xa0 = *(const f32x4*)pfA;  xa1 = *(const f32x4*)(pfA + 256);
        xb0 = *(const f32x4*)pfB;  xb1 = *(const f32x4*)(pfB + 256);

        // own LDS ops done -> barrier. No vmcnt drain: prefetch stays in flight.
        asm volatile("s_waitcnt lgkmcnt(0)" ::: "memory");
        __builtin_amdgcn_sched_barrier(0);
        __builtin_amdgcn_s_barrier();
    };

    const float* pA = xpA + 2 * (size_t)XSTP;
    const float* pB = xpB + 2 * (size_t)XSTP;
    for (int s = 0; s < 510; s += 2) {
        do_step(rdA0, wA1, xAe0, xAe1, pA,        rdB0, wB1, xBe0, xBe1, pB);         // even
        do_step(rdA1, wA0, xAo0, xAo1, pA + XSTP, rdB1, wB0, xBo0, xBo1, pB + XSTP);  // odd
        pA += 2 * (size_t)XSTP; pB += 2 * (size_t)XSTP;
    }
    do_step(rdA0, wA1, xAe0, xAe1, xpA, rdB0, wB1, xBe0, xBe1, xpB);   // step 510 (dummy pf)

    // step 511 peeled: read buf1, keep fp32 tanh values for log_softmax
    float vA0[4], vA1[4], vB0[4], vB1[4];
    {
        bf16x8 fA[8], fB[8];
#pragma unroll
        for (int kk = 0; kk < 8; ++kk) fA[kk] = *(const bf16x8*)(rdA1 + kk * 512);
#pragma unroll
        for (int kk = 0; kk < 8; ++kk) fB[kk] = *(const bf16x8*)(rdB1 + kk * 512);
        f32x4 Aa0 = xAo0, Aa1 = xAo1, Ba0 = xBo0, Ba1 = xBo1;
        f32x4 Ab0 = {0.f,0.f,0.f,0.f}, Ab1 = {0.f,0.f,0.f,0.f};
        f32x4 Bb0 = {0.f,0.f,0.f,0.f}, Bb1 = {0.f,0.f,0.f,0.f};
#pragma unroll
        for (int kk = 0; kk < 4; ++kk) {
            Aa0 = __builtin_amdgcn_mfma_f32_16x16x32_bf16(wfrag[0][kk],   fA[kk],   Aa0, 0, 0, 0);
            Aa1 = __builtin_amdgcn_mfma_f32_16x16x32_bf16(wfrag[1][kk],   fA[kk],   Aa1, 0, 0, 0);
            Ab0 = __builtin_amdgcn_mfma_f32_16x16x32_bf16(wfrag[0][kk+4], fA[kk+4], Ab0, 0, 0, 0);
            Ab1 = __builtin_amdgcn_mfma_f32_16x16x32_bf16(wfrag[1][kk+4], fA[kk+4], Ab1, 0, 0, 0);
            Ba0 = __builtin_amdgcn_mfma_f32_16x16x32_bf16(wfrag[0][kk],   fB[kk],   Ba0, 0, 0, 0);
            Ba1 = __builtin_amdgcn_mfma_f32_16x16x32_bf16(wfrag[1][kk],   fB[kk],   Ba1, 0, 0, 0);
            Bb0 = __builtin_amdgcn_mfma_f32_16x16x32_bf16(wfrag[0][kk+4], fB[kk+4], Bb0, 0, 0, 0);
            Bb1 = __builtin_amdgcn_mfma_f32_16x16x32_bf16(wfrag[1][kk+4], fB[kk+4], Bb1, 0, 0, 0);
        }
        const f32x4 dA0 = Aa0 + Ab0, dA1 = Aa1 + Ab1;
        const f32x4 dB0 = Ba0 + Bb0, dB1 = Ba1 + Bb1;
#pragma unroll
        for (int r = 0; r < 4; ++r) {
            vA0[r] = tanhC(dA0[r]); vA1[r] = tanhC(dA1[r]);
            vB0[r] = tanhC(dB0[r]); vB1[r] = tanhC(dB1[r]);
        }
    }

    // ---- log_softmax over h=256 per batch row, both streams ----
    float mA = fmaxf(fmaxf(fmaxf(vA0[0],vA0[1]),fmaxf(vA0[2],vA0[3])),
                     fmaxf(fmaxf(vA1[0],vA1[1]),fmaxf(vA1[2],vA1[3])));
    float mB = fmaxf(fmaxf(fmaxf(vB0[0],vB0[1]),fmaxf(vB0[2],vB0[3])),
                     fmaxf(fmaxf(vB1[0],vB1[1]),fmaxf(vB1[2],vB1[3])));
    mA = fmaxf(mA, __shfl_xor(mA, 16)); mA = fmaxf(mA, __shfl_xor(mA, 32));
    mB = fmaxf(mB, __shfl_xor(mB, 16)); mB = fmaxf(mB, __shfl_xor(mB, 32));
    if (lane < 16) { sred[wave][bl] = mA; sred[wave][16 + bl] = mB; }
    __syncthreads();
    float mallA = sred[0][bl], mallB = sred[0][16 + bl];
#pragma unroll
    for (int w = 1; w < 8; ++w) {
        mallA = fmaxf(mallA, sred[w][bl]);
        mallB = fmaxf(mallB, sred[w][16 + bl]);
    }
    __syncthreads();

    float sA = 0.f, sB = 0.f;
#pragma unroll
    for (int r = 0; r < 4; ++r) {
        sA += __expf(vA0[r] - mallA) + __expf(vA1[r] - mallA);
        sB += __expf(vB0[r] - mallB) + __expf(vB1[r] - mallB);
    }
    sA += __shfl_xor(sA, 16); sA += __shfl_xor(sA, 32);
    sB += __shfl_xor(sB, 16); sB += __shfl_xor(sB, 32);
    if (lane < 16) { sred[wave][bl] = sA; sred[wave][16 + bl] = sB; }
    __syncthreads();
    float totA = sred[0][bl], totB = sred[0][16 + bl];
#pragma unroll
    for (int w = 1; w < 8; ++w) { totA += sred[w][bl]; totB += sred[w][16 + bl]; }
    const float lseA = mallA + __logf(totA);
    const float lseB = mallB + __logf(totB);

    float* opA = out + (size_t)(B0 + bl) * H_SZ + wave * 32 + quad * 4;
    float* opB = out + (size_t)(B0 + 16 + bl) * H_SZ + wave * 32 + quad * 4;
    f32x4 oA0, oA1, oB0, oB1;
#pragma unroll
    for (int r = 0; r < 4; ++r) {
        oA0[r] = vA0[r] - lseA; oA1[r] = vA1[r] - lseA;
        oB0[r] = vB0[r] - lseB; oB1[r] = vB1[r] - lseB;
    }
    *(f32x4*)opA = oA0; *(f32x4*)(opA + 16) = oA1;
    *(f32x4*)opB = oB0; *(f32x4*)(opB + 16) = oB1;
}

// ---------------------------------------------------------------------------
extern "C" void kernel_launch(void* const* d_in, const int* in_sizes, int n_in,
                              void* d_out, int out_size, void* d_ws, size_t ws_size,
                              hipStream_t stream) {
    const int*   X    = (const int*)  d_in[0];
    const float* emb  = (const float*)d_in[1];
    const float* W_ih = (const float*)d_in[2];
    const float* W_hh = (const float*)d_in[3];
    const float* b_ih = (const float*)d_in[4];
    const float* b_hh = (const float*)d_in[5];
    float* out   = (float*)d_out;
    float* xproj = (float*)d_ws;   // S*B*H fp32 = 134.2 MB, fragment-linear

    prep_w_kernel<<<dim3(16), 256, 0, stream>>>(W_ih);
    embed_proj_mfma<<<dim3((S_LEN * B_SZ) / 64), 256, 0, stream>>>(
        X, emb, b_ih, b_hh, xproj);
    rnn_scan_kernel<<<dim3(B_SZ / 32), 512, 0, stream>>>(xproj, W_hh, out);
}

// Round 7
// 422.251 us; speedup vs baseline: 1.6055x; 1.6055x over previous
//
#include <hip/hip_runtime.h>
#include <math.h>

// Problem constants: S=512, B=256, V=100000, E=128, H=256
#define S_LEN 512
#define B_SZ  256
#define E_SZ  128
#define H_SZ  256
#define XSTP  65536  // floats per step in fragment-linear xproj layout (B*H)

typedef __attribute__((ext_vector_type(8))) short bf16x8;
typedef __attribute__((ext_vector_type(4))) float f32x4;

// W_ih pre-converted to bf16 hi/lo, stored in FRAGMENT-LINEAR order:
// idx = ((ht*4 + kk)*64 + lane)*8, element = W_ih[ht*16+(lane&15)][kk*32+(lane>>4)*8+j]
__device__ short g_wfh[H_SZ * E_SZ];   // 64 KB
__device__ short g_wfl[H_SZ * E_SZ];   // 64 KB

__device__ __forceinline__ unsigned pkbf(float a, float b) {
    unsigned r; asm("v_cvt_pk_bf16_f32 %0, %1, %2" : "=v"(r) : "v"(a), "v"(b));
    return r;   // lo16 = bf16(a), hi16 = bf16(b), RNE
}
__device__ __forceinline__ float fromlo(unsigned u) {
    union { unsigned u; float f; } c; c.u = u << 16; return c.f;
}
__device__ __forceinline__ float fromhi(unsigned u) {
    union { unsigned u; float f; } c; c.u = u & 0xffff0000u; return c.f;
}
__device__ __forceinline__ void cvt_hilo8(float4 a, float4 b, bf16x8& hi, bf16x8& lo) {
    unsigned h0 = pkbf(a.x, a.y), h1 = pkbf(a.z, a.w);
    unsigned h2 = pkbf(b.x, b.y), h3 = pkbf(b.z, b.w);
    unsigned l0 = pkbf(a.x - fromlo(h0), a.y - fromhi(h0));
    unsigned l1 = pkbf(a.z - fromlo(h1), a.w - fromhi(h1));
    unsigned l2 = pkbf(b.x - fromlo(h2), b.y - fromhi(h2));
    unsigned l3 = pkbf(b.z - fromlo(h3), b.w - fromhi(h3));
    union { bf16x8 v; unsigned u[4]; } H, L;
    H.u[0] = h0; H.u[1] = h1; H.u[2] = h2; H.u[3] = h3;
    L.u[0] = l0; L.u[1] = l1; L.u[2] = l2; L.u[3] = l3;
    hi = H.v; lo = L.v;
}

// tanh(v) = 1 - 2/(exp2(C*v)+1), C = 2*log2(e). Numerics validated R4/R6.
__device__ __forceinline__ float tanhC(float v) {
    float e = __builtin_amdgcn_exp2f(v * 2.8853900818f);
    return fmaf(-2.f, __builtin_amdgcn_rcpf(e + 1.f), 1.f);
}

// ---------------------------------------------------------------------------
// Kernel 0: one-time W_ih -> bf16 hi/lo in fragment-linear order. (R6, verified)
// ---------------------------------------------------------------------------
__global__ void prep_w_kernel(const float* __restrict__ W_ih) {
    const int t  = blockIdx.x * 256 + threadIdx.x;   // 0..4095
    const int l  = t & 63;
    const int kk = (t >> 6) & 3;
    const int ht = t >> 8;                            // 0..15
    const int h  = ht * 16 + (l & 15);
    const int k0 = kk * 32 + (l >> 4) * 8;
    const float* wp = W_ih + h * E_SZ + k0;
    float4 a = *(const float4*)wp;
    float4 b = *(const float4*)(wp + 4);
    bf16x8 hi, lo;
    cvt_hilo8(a, b, hi, lo);
    *(bf16x8*)&g_wfh[t * 8] = hi;
    *(bf16x8*)&g_wfl[t * 8] = lo;
}

// ---------------------------------------------------------------------------
// Kernel 1: embed gather + projection (R6, verified, unchanged).
// xproj fragment-linear: float idx = s*XSTP + ((b>>4)*16 + ht)*256 + lane*4 + r
// with ht = h>>4, lane = ((h>>2)&3)*16 + (b&15).
// ---------------------------------------------------------------------------
__global__ __launch_bounds__(256, 2) void embed_proj_mfma(
    const int*   __restrict__ X,
    const float* __restrict__ emb,
    const float* __restrict__ b_ih,
    const float* __restrict__ b_hh,
    float*       __restrict__ xproj)
{
    __shared__ int   toks[64];
    __shared__ short BtH[4][4][64][8];   // [ntile][kk][lane][j] hi, 16KB
    __shared__ short BtL[4][4][64][8];   // lo, 16KB

    const int tid  = threadIdx.x;
    const int wave = tid >> 6;           // 0..3
    const int lane = tid & 63;
    const int bl   = lane & 15;
    const int quad = lane >> 4;
    const size_t row0 = (size_t)blockIdx.x * 64;   // rows = s*256 + b
    const int s_idx = (int)(row0 >> 8);
    const int bbase = (int)(row0 & 255);

    if (tid < 64) toks[tid] = X[row0 + tid];
    __syncthreads();

    {
        const int r  = tid >> 2;         // 0..63 row
        const int kk = tid & 3;          // k-chunk of 32
        const float* ep = emb + (size_t)toks[r] * E_SZ + kk * 32;
#pragma unroll
        for (int q = 0; q < 4; ++q) {
            float4 a = *(const float4*)(ep + q * 8);
            float4 b = *(const float4*)(ep + q * 8 + 4);
            bf16x8 fh, fl;
            cvt_hilo8(a, b, fh, fl);
            *(bf16x8*)&BtH[r >> 4][kk][q * 16 + (r & 15)][0] = fh;
            *(bf16x8*)&BtL[r >> 4][kk][q * 16 + (r & 15)][0] = fl;
        }
    }
    __syncthreads();

#pragma unroll
    for (int mp = 0; mp < 2; ++mp) {
        bf16x8 wh[2][4], wl[2][4];
#pragma unroll
        for (int i = 0; i < 2; ++i) {
            const int ht = wave * 4 + mp * 2 + i;
#pragma unroll
            for (int kk = 0; kk < 4; ++kk) {
                wh[i][kk] = *(const bf16x8*)&g_wfh[((ht * 4 + kk) * 64 + lane) * 8];
                wl[i][kk] = *(const bf16x8*)&g_wfl[((ht * 4 + kk) * 64 + lane) * 8];
            }
        }

        f32x4 acc[2][4];
#pragma unroll
        for (int i = 0; i < 2; ++i)
#pragma unroll
            for (int nt = 0; nt < 4; ++nt) acc[i][nt] = (f32x4){0.f, 0.f, 0.f, 0.f};

#pragma unroll
        for (int kk = 0; kk < 4; ++kk) {
            bf16x8 bh[4], blo[4];
#pragma unroll
            for (int nt = 0; nt < 4; ++nt) {
                bh[nt]  = *(const bf16x8*)&BtH[nt][kk][lane][0];
                blo[nt] = *(const bf16x8*)&BtL[nt][kk][lane][0];
            }
#pragma unroll
            for (int i = 0; i < 2; ++i)
#pragma unroll
                for (int nt = 0; nt < 4; ++nt) {
                    f32x4 a = acc[i][nt];
                    a = __builtin_amdgcn_mfma_f32_16x16x32_bf16(wh[i][kk], bh[nt],  a, 0, 0, 0);
                    a = __builtin_amdgcn_mfma_f32_16x16x32_bf16(wh[i][kk], blo[nt], a, 0, 0, 0);
                    a = __builtin_amdgcn_mfma_f32_16x16x32_bf16(wl[i][kk], bh[nt],  a, 0, 0, 0);
                    acc[i][nt] = a;
                }
        }

#pragma unroll
        for (int i = 0; i < 2; ++i) {
            const int ht = wave * 4 + mp * 2 + i;
            const int hb = ht * 16 + quad * 4;
            float4 bi  = *(const float4*)&b_ih[hb];
            float4 bh4 = *(const float4*)&b_hh[hb];
#pragma unroll
            for (int nt = 0; nt < 4; ++nt) {
                const int b   = bbase + nt * 16;              // + bl via lane
                const int blk = b >> 5, str = (b >> 4) & 1;
                f32x4 o = acc[i][nt];
                o[0] += bi.x + bh4.x; o[1] += bi.y + bh4.y;
                o[2] += bi.z + bh4.z; o[3] += bi.w + bh4.w;
                float* dst = xproj + (size_t)s_idx * XSTP
                           + ((((blk * 2 + str) * 8 + (ht >> 1)) * 2 + (ht & 1)) * 64 + lane) * 4;
                *(f32x4*)dst = o;
            }
        }
    }
}

// ---------------------------------------------------------------------------
// Kernel 2 (v7): single-stream 8-wave scan — v3 structure (measured best,
// 311 us) + validated improvements only:
//  - C-init with xp (first MFMA chain's accumulator = xp; layout-identical)
//  - tanhC (exp2-based, one mul shorter)
//  - fragment-linear xp reads (1KB-contiguous wave loads; verified in R6)
// 16 blocks x 16 batch; per-CU per-step budget: LDS 768 + MFMA 621 + tail.
// ---------------------------------------------------------------------------
__global__ __launch_bounds__(512) void rnn_scan_kernel(
    const float* __restrict__ xproj,
    const float* __restrict__ W_hh,
    float*       __restrict__ out)
{
    const int tid  = threadIdx.x;
    const int wave = tid >> 6;      // 0..7
    const int lane = tid & 63;
    const int bl   = lane & 15;
    const int quad = lane >> 4;
    const int B0   = blockIdx.x * 16;

    __shared__ short HB[2][4096];   // 2 x 8KB state buffers
    __shared__ float sred[8][16];

    // ---- A-operand: W_hh fragments ----
    // lane holds A[m = wave*32 + mt*16 + bl][k = kk*32 + quad*8 + j]
    bf16x8 wfrag[2][8];
#pragma unroll
    for (int mt = 0; mt < 2; ++mt) {
        const int h = wave * 32 + mt * 16 + bl;
#pragma unroll
        for (int kk = 0; kk < 8; ++kk) {
            const float* wp = W_hh + (size_t)h * H_SZ + kk * 32 + quad * 8;
            float4 a = *(const float4*)wp;
            float4 b = *(const float4*)(wp + 4);
            union { bf16x8 v; unsigned u[4]; } F;
            F.u[0] = pkbf(a.x, a.y); F.u[1] = pkbf(a.z, a.w);
            F.u[2] = pkbf(b.x, b.y); F.u[3] = pkbf(b.z, b.w);
            wfrag[mt][kk] = F.v;
        }
    }

    ((int4*)&HB[0][0])[tid] = make_int4(0, 0, 0, 0);   // zero buf0 (8KB)

    const short* rd0 = &HB[0][0] + lane * 8;
    const short* rd1 = &HB[1][0] + lane * 8;

    // write slot: h -> shorts offset (h>>5)*512 + ((h>>3)&3)*128 + bl*8 + (h&7)
    const int wo = wave * 512 + (quad >> 1) * 128 + bl * 8 + (quad & 1) * 4;
    short* const w0 = &HB[0][0] + wo;
    short* const w1 = &HB[1][0] + wo;

    // xp base, fragment-linear: within-step float off (g*16 + wave*2 + mt)*256
    // + lane*4, with g = blockIdx.x (16-batch group). mt=1 at +256 floats.
    const float* xpb = xproj + ((size_t)blockIdx.x * 16 + wave * 2) * 256 + lane * 4;

    // distance-2 prefetch register sets (even/odd parity)
    f32x4 xe0 = *(const f32x4*)(xpb);
    f32x4 xe1 = *(const f32x4*)(xpb + 256);
    f32x4 xo0 = *(const f32x4*)(xpb + XSTP);
    f32x4 xo1 = *(const f32x4*)(xpb + XSTP + 256);

    __syncthreads();

    auto do_step = [&](const short* rd, short* wr,
                       f32x4& x0, f32x4& x1, const float* pf) {
        // B-fragments: 8 x ds_read_b128, conflict-free contiguous
        bf16x8 bf[8];
#pragma unroll
        for (int kk = 0; kk < 8; ++kk)
            bf[kk] = *(const bf16x8*)(rd + kk * 512);

        // 4 chains of depth 4 (2 m-tiles x 2 k-halves); xp as C-init
        f32x4 a0 = x0, a1 = x1;
        f32x4 b0 = {0.f,0.f,0.f,0.f}, b1 = {0.f,0.f,0.f,0.f};
#pragma unroll
        for (int kk = 0; kk < 4; ++kk) {
            a0 = __builtin_amdgcn_mfma_f32_16x16x32_bf16(wfrag[0][kk],   bf[kk],   a0, 0, 0, 0);
            a1 = __builtin_amdgcn_mfma_f32_16x16x32_bf16(wfrag[1][kk],   bf[kk],   a1, 0, 0, 0);
            b0 = __builtin_amdgcn_mfma_f32_16x16x32_bf16(wfrag[0][kk+4], bf[kk+4], b0, 0, 0, 0);
            b1 = __builtin_amdgcn_mfma_f32_16x16x32_bf16(wfrag[1][kk+4], bf[kk+4], b1, 0, 0, 0);
        }
        const f32x4 d0 = a0 + b0, d1 = a1 + b1;

        // epilogue: tanh, pack bf16, store next state
        float t0 = tanhC(d0[0]), t1 = tanhC(d0[1]), t2 = tanhC(d0[2]), t3 = tanhC(d0[3]);
        float u0 = tanhC(d1[0]), u1 = tanhC(d1[1]), u2 = tanhC(d1[2]), u3 = tanhC(d1[3]);
        *(uint2*)wr         = make_uint2(pkbf(t0, t1), pkbf(t2, t3));
        *(uint2*)(wr + 256) = make_uint2(pkbf(u0, u1), pkbf(u2, u3));

        // prefetch for step s+2 directly into the just-consumed registers
        // (v3-proven: consumed 2 full steps after issue; no early drain)
        x0 = *(const f32x4*)pf;
        x1 = *(const f32x4*)(pf + 256);

        // own LDS ops done -> barrier. No vmcnt drain: prefetch stays in flight.
        asm volatile("s_waitcnt lgkmcnt(0)" ::: "memory");
        __builtin_amdgcn_sched_barrier(0);
        __builtin_amdgcn_s_barrier();
    };

    const float* pf = xpb + 2 * (size_t)XSTP;
    for (int s = 0; s < 510; s += 2) {
        do_step(rd0, w1, xe0, xe1, pf);          // even step s   (pf -> s+2)
        do_step(rd1, w0, xo0, xo1, pf + XSTP);   // odd step s+1  (pf -> s+3)
        pf += 2 * (size_t)XSTP;
    }
    do_step(rd0, w1, xe0, xe1, xpb);             // step 510 (dummy in-bounds pf)

    // step 511 peeled: read buf1, keep fp32 tanh values for log_softmax
    float vf0[4], vf1[4];
    {
        bf16x8 bf[8];
#pragma unroll
        for (int kk = 0; kk < 8; ++kk)
            bf[kk] = *(const bf16x8*)(rd1 + kk * 512);
        f32x4 a0 = xo0, a1 = xo1;
        f32x4 b0 = {0.f,0.f,0.f,0.f}, b1 = {0.f,0.f,0.f,0.f};
#pragma unroll
        for (int kk = 0; kk < 4; ++kk) {
            a0 = __builtin_amdgcn_mfma_f32_16x16x32_bf16(wfrag[0][kk],   bf[kk],   a0, 0, 0, 0);
            a1 = __builtin_amdgcn_mfma_f32_16x16x32_bf16(wfrag[1][kk],   bf[kk],   a1, 0, 0, 0);
            b0 = __builtin_amdgcn_mfma_f32_16x16x32_bf16(wfrag[0][kk+4], bf[kk+4], b0, 0, 0, 0);
            b1 = __builtin_amdgcn_mfma_f32_16x16x32_bf16(wfrag[1][kk+4], bf[kk+4], b1, 0, 0, 0);
        }
        const f32x4 d0 = a0 + b0, d1 = a1 + b1;
#pragma unroll
        for (int r = 0; r < 4; ++r) {
            vf0[r] = tanhC(d0[r]);
            vf1[r] = tanhC(d1[r]);
        }
    }

    // ---- log_softmax over h=256 for each batch row bl ----
    float m = fmaxf(fmaxf(fmaxf(vf0[0], vf0[1]), fmaxf(vf0[2], vf0[3])),
                    fmaxf(fmaxf(vf1[0], vf1[1]), fmaxf(vf1[2], vf1[3])));
    m = fmaxf(m, __shfl_xor(m, 16));
    m = fmaxf(m, __shfl_xor(m, 32));
    if (lane < 16) sred[wave][bl] = m;
    __syncthreads();
    float mall = sred[0][bl];
#pragma unroll
    for (int w = 1; w < 8; ++w) mall = fmaxf(mall, sred[w][bl]);
    __syncthreads();

    float ss = 0.f;
#pragma unroll
    for (int r = 0; r < 4; ++r)
        ss += __expf(vf0[r] - mall) + __expf(vf1[r] - mall);
    ss += __shfl_xor(ss, 16);
    ss += __shfl_xor(ss, 32);
    if (lane < 16) sred[wave][bl] = ss;
    __syncthreads();
    float tot = sred[0][bl];
#pragma unroll
    for (int w = 1; w < 8; ++w) tot += sred[w][bl];
    const float lse = mall + __logf(tot);

    f32x4 o0, o1;
#pragma unroll
    for (int r = 0; r < 4; ++r) { o0[r] = vf0[r] - lse; o1[r] = vf1[r] - lse; }
    float* op = out + (size_t)(B0 + bl) * H_SZ + wave * 32 + quad * 4;
    *(f32x4*)op        = o0;
    *(f32x4*)(op + 16) = o1;
}

// ---------------------------------------------------------------------------
extern "C" void kernel_launch(void* const* d_in, const int* in_sizes, int n_in,
                              void* d_out, int out_size, void* d_ws, size_t ws_size,
                              hipStream_t stream) {
    const int*   X    = (const int*)  d_in[0];
    const float* emb  = (const float*)d_in[1];
    const float* W_ih = (const float*)d_in[2];
    const float* W_hh = (const float*)d_in[3];
    const float* b_ih = (const float*)d_in[4];
    const float* b_hh = (const float*)d_in[5];
    float* out   = (float*)d_out;
    float* xproj = (float*)d_ws;   // S*B*H fp32 = 134.2 MB, fragment-linear

    prep_w_kernel<<<dim3(16), 256, 0, stream>>>(W_ih);
    embed_proj_mfma<<<dim3((S_LEN * B_SZ) / 64), 256, 0, stream>>>(
        X, emb, b_ih, b_hh, xproj);
    rnn_scan_kernel<<<dim3(B_SZ / 16), 512, 0, stream>>>(xproj, W_hh, out);
}

// Round 9
// 407.449 us; speedup vs baseline: 1.6638x; 1.0363x over previous
//
#include <hip/hip_runtime.h>
#include <math.h>

// Problem constants: S=512, B=256, V=100000, E=128, H=256
#define S_LEN 512
#define B_SZ  256
#define E_SZ  128
#define H_SZ  256
#define XSTP  65536  // floats per step in fragment-linear xproj layout (B*H)

typedef __attribute__((ext_vector_type(8))) short bf16x8;
typedef __attribute__((ext_vector_type(4))) float f32x4;

// W_ih pre-converted to bf16 hi/lo, stored in FRAGMENT-LINEAR order:
// idx = ((ht*4 + kk)*64 + lane)*8, element = W_ih[ht*16+(lane&15)][kk*32+(lane>>4)*8+j]
__device__ short g_wfh[H_SZ * E_SZ];   // 64 KB
__device__ short g_wfl[H_SZ * E_SZ];   // 64 KB

__device__ __forceinline__ unsigned pkbf(float a, float b) {
    unsigned r; asm("v_cvt_pk_bf16_f32 %0, %1, %2" : "=v"(r) : "v"(a), "v"(b));
    return r;   // lo16 = bf16(a), hi16 = bf16(b), RNE
}
__device__ __forceinline__ float fromlo(unsigned u) {
    union { unsigned u; float f; } c; c.u = u << 16; return c.f;
}
__device__ __forceinline__ float fromhi(unsigned u) {
    union { unsigned u; float f; } c; c.u = u & 0xffff0000u; return c.f;
}
__device__ __forceinline__ void cvt_hilo8(float4 a, float4 b, bf16x8& hi, bf16x8& lo) {
    unsigned h0 = pkbf(a.x, a.y), h1 = pkbf(a.z, a.w);
    unsigned h2 = pkbf(b.x, b.y), h3 = pkbf(b.z, b.w);
    unsigned l0 = pkbf(a.x - fromlo(h0), a.y - fromhi(h0));
    unsigned l1 = pkbf(a.z - fromlo(h1), a.w - fromhi(h1));
    unsigned l2 = pkbf(b.x - fromlo(h2), b.y - fromhi(h2));
    unsigned l3 = pkbf(b.z - fromlo(h3), b.w - fromhi(h3));
    union { bf16x8 v; unsigned u[4]; } H, L;
    H.u[0] = h0; H.u[1] = h1; H.u[2] = h2; H.u[3] = h3;
    L.u[0] = l0; L.u[1] = l1; L.u[2] = l2; L.u[3] = l3;
    hi = H.v; lo = L.v;
}

// tanh(v) = 1 - 2/(exp2(C*v)+1), C = 2*log2(e). Numerics validated R4/R6/R7.
__device__ __forceinline__ float tanhC(float v) {
    float e = __builtin_amdgcn_exp2f(v * 2.8853900818f);
    return fmaf(-2.f, __builtin_amdgcn_rcpf(e + 1.f), 1.f);
}

// ---------------------------------------------------------------------------
// Kernel 0: one-time W_ih -> bf16 hi/lo in fragment-linear order. (verified)
// ---------------------------------------------------------------------------
__global__ void prep_w_kernel(const float* __restrict__ W_ih) {
    const int t  = blockIdx.x * 256 + threadIdx.x;   // 0..4095
    const int l  = t & 63;
    const int kk = (t >> 6) & 3;
    const int ht = t >> 8;                            // 0..15
    const int h  = ht * 16 + (l & 15);
    const int k0 = kk * 32 + (l >> 4) * 8;
    const float* wp = W_ih + h * E_SZ + k0;
    float4 a = *(const float4*)wp;
    float4 b = *(const float4*)(wp + 4);
    bf16x8 hi, lo;
    cvt_hilo8(a, b, hi, lo);
    *(bf16x8*)&g_wfh[t * 8] = hi;
    *(bf16x8*)&g_wfl[t * 8] = lo;
}

// ---------------------------------------------------------------------------
// Kernel 1: embed gather + projection — EXACT R7 version (verified at 422us
// total). R8's hoist + __launch_bounds__(256,4) forced ~120 spilled VGPRs
// (~250MB scratch across the grid): prime suspect for the post-capture
// state corruption (pre-capture launch OK, all later executions wrong).
// Reverted wholesale; no spill here (bounds ,2 -> 256-VGPR cap).
// ---------------------------------------------------------------------------
__global__ __launch_bounds__(256, 2) void embed_proj_mfma(
    const int*   __restrict__ X,
    const float* __restrict__ emb,
    const float* __restrict__ b_ih,
    const float* __restrict__ b_hh,
    float*       __restrict__ xproj)
{
    __shared__ int   toks[64];
    __shared__ short BtH[4][4][64][8];   // [ntile][kk][lane][j] hi, 16KB
    __shared__ short BtL[4][4][64][8];   // lo, 16KB

    const int tid  = threadIdx.x;
    const int wave = tid >> 6;           // 0..3
    const int lane = tid & 63;
    const int bl   = lane & 15;
    const int quad = lane >> 4;
    const size_t row0 = (size_t)blockIdx.x * 64;   // rows = s*256 + b
    const int s_idx = (int)(row0 >> 8);
    const int bbase = (int)(row0 & 255);

    if (tid < 64) toks[tid] = X[row0 + tid];
    __syncthreads();

    {
        const int r  = tid >> 2;         // 0..63 row
        const int kk = tid & 3;          // k-chunk of 32
        const float* ep = emb + (size_t)toks[r] * E_SZ + kk * 32;
#pragma unroll
        for (int q = 0; q < 4; ++q) {
            float4 a = *(const float4*)(ep + q * 8);
            float4 b = *(const float4*)(ep + q * 8 + 4);
            bf16x8 fh, fl;
            cvt_hilo8(a, b, fh, fl);
            *(bf16x8*)&BtH[r >> 4][kk][q * 16 + (r & 15)][0] = fh;
            *(bf16x8*)&BtL[r >> 4][kk][q * 16 + (r & 15)][0] = fl;
        }
    }
    __syncthreads();

#pragma unroll
    for (int mp = 0; mp < 2; ++mp) {
        bf16x8 wh[2][4], wl[2][4];
#pragma unroll
        for (int i = 0; i < 2; ++i) {
            const int ht = wave * 4 + mp * 2 + i;
#pragma unroll
            for (int kk = 0; kk < 4; ++kk) {
                wh[i][kk] = *(const bf16x8*)&g_wfh[((ht * 4 + kk) * 64 + lane) * 8];
                wl[i][kk] = *(const bf16x8*)&g_wfl[((ht * 4 + kk) * 64 + lane) * 8];
            }
        }

        f32x4 acc[2][4];
#pragma unroll
        for (int i = 0; i < 2; ++i)
#pragma unroll
            for (int nt = 0; nt < 4; ++nt) acc[i][nt] = (f32x4){0.f, 0.f, 0.f, 0.f};

#pragma unroll
        for (int kk = 0; kk < 4; ++kk) {
            bf16x8 bh[4], blo[4];
#pragma unroll
            for (int nt = 0; nt < 4; ++nt) {
                bh[nt]  = *(const bf16x8*)&BtH[nt][kk][lane][0];
                blo[nt] = *(const bf16x8*)&BtL[nt][kk][lane][0];
            }
#pragma unroll
            for (int i = 0; i < 2; ++i)
#pragma unroll
                for (int nt = 0; nt < 4; ++nt) {
                    f32x4 a = acc[i][nt];
                    a = __builtin_amdgcn_mfma_f32_16x16x32_bf16(wh[i][kk], bh[nt],  a, 0, 0, 0);
                    a = __builtin_amdgcn_mfma_f32_16x16x32_bf16(wh[i][kk], blo[nt], a, 0, 0, 0);
                    a = __builtin_amdgcn_mfma_f32_16x16x32_bf16(wl[i][kk], bh[nt],  a, 0, 0, 0);
                    acc[i][nt] = a;
                }
        }

#pragma unroll
        for (int i = 0; i < 2; ++i) {
            const int ht = wave * 4 + mp * 2 + i;
            const int hb = ht * 16 + quad * 4;
            float4 bi  = *(const float4*)&b_ih[hb];
            float4 bh4 = *(const float4*)&b_hh[hb];
#pragma unroll
            for (int nt = 0; nt < 4; ++nt) {
                const int b   = bbase + nt * 16;              // + bl via lane
                const int blk = b >> 5, str = (b >> 4) & 1;
                f32x4 o = acc[i][nt];
                o[0] += bi.x + bh4.x; o[1] += bi.y + bh4.y;
                o[2] += bi.z + bh4.z; o[3] += bi.w + bh4.w;
                float* dst = xproj + (size_t)s_idx * XSTP
                           + ((((blk * 2 + str) * 8 + (ht >> 1)) * 2 + (ht & 1)) * 64 + lane) * 4;
                *(f32x4*)dst = o;
            }
        }
    }
}

// ---------------------------------------------------------------------------
// Kernel 2 (v8): R7 scan + XOR bank-swizzle + grouped epilogue (kept from
// R8 — algebra-verified involution addr^32*bit6(addr) on BOTH write and
// read sides; call-1 of R8 produced the exact canonical absmax, confirming
// functional correctness; zero scratch use).
// ---------------------------------------------------------------------------
__global__ __launch_bounds__(512) void rnn_scan_kernel(
    const float* __restrict__ xproj,
    const float* __restrict__ W_hh,
    float*       __restrict__ out)
{
    const int tid  = threadIdx.x;
    const int wave = tid >> 6;      // 0..7
    const int lane = tid & 63;
    const int bl   = lane & 15;
    const int quad = lane >> 4;
    const int B0   = blockIdx.x * 16;

    __shared__ short HB[2][4096];   // 2 x 8KB state buffers
    __shared__ float sred[8][16];

    // ---- A-operand: W_hh fragments ----
    bf16x8 wfrag[2][8];
#pragma unroll
    for (int mt = 0; mt < 2; ++mt) {
        const int h = wave * 32 + mt * 16 + bl;
#pragma unroll
        for (int kk = 0; kk < 8; ++kk) {
            const float* wp = W_hh + (size_t)h * H_SZ + kk * 32 + quad * 8;
            float4 a = *(const float4*)wp;
            float4 b = *(const float4*)(wp + 4);
            union { bf16x8 v; unsigned u[4]; } F;
            F.u[0] = pkbf(a.x, a.y); F.u[1] = pkbf(a.z, a.w);
            F.u[2] = pkbf(b.x, b.y); F.u[3] = pkbf(b.z, b.w);
            wfrag[mt][kk] = F.v;
        }
    }

    ((int4*)&HB[0][0])[tid] = make_int4(0, 0, 0, 0);   // zero buf0 (8KB)

    // bank swizzle: flip addr-bit5 iff addr-bit6 (bl bit3), both sides
    const int xsw = (bl & 8) << 2;

    const short* rd0 = &HB[0][0] + ((lane * 8) ^ xsw);
    const short* rd1 = &HB[1][0] + ((lane * 8) ^ xsw);

    // write slot: h -> shorts offset (h>>5)*512 + ((h>>3)&3)*128 + bl*8 + (h&7)
    const int wo = (wave * 512 + (quad >> 1) * 128 + bl * 8 + (quad & 1) * 4) ^ xsw;
    short* const w0 = &HB[0][0] + wo;
    short* const w1 = &HB[1][0] + wo;

    // xp base, fragment-linear (verified R7)
    const float* xpb = xproj + ((size_t)blockIdx.x * 16 + wave * 2) * 256 + lane * 4;

    // distance-2 prefetch register sets (even/odd parity)
    f32x4 xe0 = *(const f32x4*)(xpb);
    f32x4 xe1 = *(const f32x4*)(xpb + 256);
    f32x4 xo0 = *(const f32x4*)(xpb + XSTP);
    f32x4 xo1 = *(const f32x4*)(xpb + XSTP + 256);

    __syncthreads();

    auto do_step = [&](const short* rd, short* wr,
                       f32x4& x0, f32x4& x1, const float* pf) {
        // B-fragments: 8 x ds_read_b128 (conflict-free after swizzle)
        bf16x8 bf[8];
#pragma unroll
        for (int kk = 0; kk < 8; ++kk)
            bf[kk] = *(const bf16x8*)(rd + kk * 512);

        // mt0's chains first, then mt1's: d0's epilogue VALU overlaps
        // mt1's MFMA completion.
        f32x4 a0 = x0, b0 = {0.f,0.f,0.f,0.f};
#pragma unroll
        for (int kk = 0; kk < 4; ++kk) {
            a0 = __builtin_amdgcn_mfma_f32_16x16x32_bf16(wfrag[0][kk],   bf[kk],   a0, 0, 0, 0);
            b0 = __builtin_amdgcn_mfma_f32_16x16x32_bf16(wfrag[0][kk+4], bf[kk+4], b0, 0, 0, 0);
        }
        f32x4 a1 = x1, b1 = {0.f,0.f,0.f,0.f};
#pragma unroll
        for (int kk = 0; kk < 4; ++kk) {
            a1 = __builtin_amdgcn_mfma_f32_16x16x32_bf16(wfrag[1][kk],   bf[kk],   a1, 0, 0, 0);
            b1 = __builtin_amdgcn_mfma_f32_16x16x32_bf16(wfrag[1][kk+4], bf[kk+4], b1, 0, 0, 0);
        }

        const f32x4 d0 = a0 + b0;
        float t0 = tanhC(d0[0]), t1 = tanhC(d0[1]), t2 = tanhC(d0[2]), t3 = tanhC(d0[3]);
        *(uint2*)wr = make_uint2(pkbf(t0, t1), pkbf(t2, t3));

        const f32x4 d1 = a1 + b1;
        float u0 = tanhC(d1[0]), u1 = tanhC(d1[1]), u2 = tanhC(d1[2]), u3 = tanhC(d1[3]);
        *(uint2*)(wr + 256) = make_uint2(pkbf(u0, u1), pkbf(u2, u3));

        // prefetch for step s+2 directly into the just-consumed registers
        x0 = *(const f32x4*)pf;
        x1 = *(const f32x4*)(pf + 256);

        // own LDS ops done -> barrier. No vmcnt drain: prefetch stays in flight.
        asm volatile("s_waitcnt lgkmcnt(0)" ::: "memory");
        __builtin_amdgcn_sched_barrier(0);
        __builtin_amdgcn_s_barrier();
    };

    const float* pf = xpb + 2 * (size_t)XSTP;
    for (int s = 0; s < 510; s += 2) {
        do_step(rd0, w1, xe0, xe1, pf);          // even step s   (pf -> s+2)
        do_step(rd1, w0, xo0, xo1, pf + XSTP);   // odd step s+1  (pf -> s+3)
        pf += 2 * (size_t)XSTP;
    }
    do_step(rd0, w1, xe0, xe1, xpb);             // step 510 (dummy in-bounds pf)

    // step 511 peeled: read buf1, keep fp32 tanh values for log_softmax
    float vf0[4], vf1[4];
    {
        bf16x8 bf[8];
#pragma unroll
        for (int kk = 0; kk < 8; ++kk)
            bf[kk] = *(const bf16x8*)(rd1 + kk * 512);
        f32x4 a0 = xo0, a1 = xo1;
        f32x4 b0 = {0.f,0.f,0.f,0.f}, b1 = {0.f,0.f,0.f,0.f};
#pragma unroll
        for (int kk = 0; kk < 4; ++kk) {
            a0 = __builtin_amdgcn_mfma_f32_16x16x32_bf16(wfrag[0][kk],   bf[kk],   a0, 0, 0, 0);
            a1 = __builtin_amdgcn_mfma_f32_16x16x32_bf16(wfrag[1][kk],   bf[kk],   a1, 0, 0, 0);
            b0 = __builtin_amdgcn_mfma_f32_16x16x32_bf16(wfrag[0][kk+4], bf[kk+4], b0, 0, 0, 0);
            b1 = __builtin_amdgcn_mfma_f32_16x16x32_bf16(wfrag[1][kk+4], bf[kk+4], b1, 0, 0, 0);
        }
        const f32x4 d0 = a0 + b0, d1 = a1 + b1;
#pragma unroll
        for (int r = 0; r < 4; ++r) {
            vf0[r] = tanhC(d0[r]);
            vf1[r] = tanhC(d1[r]);
        }
    }

    // ---- log_softmax over h=256 for each batch row bl ----
    float m = fmaxf(fmaxf(fmaxf(vf0[0], vf0[1]), fmaxf(vf0[2], vf0[3])),
                    fmaxf(fmaxf(vf1[0], vf1[1]), fmaxf(vf1[2], vf1[3])));
    m = fmaxf(m, __shfl_xor(m, 16));
    m = fmaxf(m, __shfl_xor(m, 32));
    if (lane < 16) sred[wave][bl] = m;
    __syncthreads();
    float mall = sred[0][bl];
#pragma unroll
    for (int w = 1; w < 8; ++w) mall = fmaxf(mall, sred[w][bl]);
    __syncthreads();

    float ss = 0.f;
#pragma unroll
    for (int r = 0; r < 4; ++r)
        ss += __expf(vf0[r] - mall) + __expf(vf1[r] - mall);
    ss += __shfl_xor(ss, 16);
    ss += __shfl_xor(ss, 32);
    if (lane < 16) sred[wave][bl] = ss;
    __syncthreads();
    float tot = sred[0][bl];
#pragma unroll
    for (int w = 1; w < 8; ++w) tot += sred[w][bl];
    const float lse = mall + __logf(tot);

    f32x4 o0, o1;
#pragma unroll
    for (int r = 0; r < 4; ++r) { o0[r] = vf0[r] - lse; o1[r] = vf1[r] - lse; }
    float* op = out + (size_t)(B0 + bl) * H_SZ + wave * 32 + quad * 4;
    *(f32x4*)op        = o0;
    *(f32x4*)(op + 16) = o1;
}

// ---------------------------------------------------------------------------
extern "C" void kernel_launch(void* const* d_in, const int* in_sizes, int n_in,
                              void* d_out, int out_size, void* d_ws, size_t ws_size,
                              hipStream_t stream) {
    const int*   X    = (const int*)  d_in[0];
    const float* emb  = (const float*)d_in[1];
    const float* W_ih = (const float*)d_in[2];
    const float* W_hh = (const float*)d_in[3];
    const float* b_ih = (const float*)d_in[4];
    const float* b_hh = (const float*)d_in[5];
    float* out   = (float*)d_out;
    float* xproj = (float*)d_ws;   // S*B*H fp32 = 134.2 MB, fragment-linear

    prep_w_kernel<<<dim3(16), 256, 0, stream>>>(W_ih);
    embed_proj_mfma<<<dim3((S_LEN * B_SZ) / 64), 256, 0, stream>>>(
        X, emb, b_ih, b_hh, xproj);
    rnn_scan_kernel<<<dim3(B_SZ / 16), 512, 0, stream>>>(xproj, W_hh, out);
}